// Round 7
// baseline (144.599 us; speedup 1.0000x reference)
//
#include <hip/hip_runtime.h>

#define HH 512
#define WW 512
#define NPLANE 48
#define BY 128
#define BX 128           // block covers 128 cols: 4 waves x 2 pipes x 16 cols
#define CHK 16
#define RING 32          // logical ring slots (row r -> slot r & 31)
#define PSTR 40          // physical col stride in shorts (80 B): proven layout
#define KS 11

typedef __attribute__((ext_vector_type(8))) short short8;   // 8 bf16 (A/B frag)
typedef __attribute__((ext_vector_type(4))) float floatx4;  // 4 fp32 (C/D frag)
typedef __attribute__((ext_vector_type(2))) float float2v;
typedef __attribute__((ext_vector_type(2))) __bf16 bf16x2v;

// exact RNE pack (weights, once)
__device__ inline unsigned pk2bf_rne(float a, float b) {
    union { float f; unsigned u; } ua, ub;
    ua.f = a; ub.f = b;
    unsigned lo = (ua.u + 0x7FFFu + ((ua.u >> 16) & 1u)) >> 16;
    unsigned hi = (ub.u + 0x7FFFu + ((ub.u >> 16) & 1u)) >> 16;
    return lo | (hi << 16);
}

// hot-path pack: float2v -> bf16x2; lowers to v_cvt_pk_bf16_f32 on gfx950
__device__ inline unsigned pkbf2(float2v f) {
    bf16x2v v = __builtin_convertvector(f, bf16x2v);
    return __builtin_bit_cast(unsigned, v);
}

struct Raw   { float4 p0, p1, t0, t1; };
struct Frags { short8 p, t, q, pt; };

// Fully-MFMA SSIM, 4 ring channels: p, t, q=p^2+t^2, pt.
//
// TWO INDEPENDENT PIPELINES PER WAVE (round 7). Evidence through round 6:
// three different schedules all pin at 52-55us; VALUBusy dropped 32->27.6%
// with no dur change (not VALU-bound); cached-input replays (49KB fetched)
// also run 52us (not HBM-BW-bound). Diagnosis: correlated-stall latency bind
// -- every wave's body has a vmcnt/lgkmcnt wait, all blocks run lockstep, so
// all 6 waves/SIMD stall together (~60% SIMD idle; 28% VALUBusy == pure issue
// demand). Fix: each wave runs TWO independent 16-col pipelines (own ring,
// own load stream). When pipe A sits at its waitcnt, pipe B's independent
// work in the SAME wave covers the stall -- immune to cross-wave correlation.
// Each pipe is single-buffered: load-to-use = 1 body, and a body now holds
// BOTH pipes' compute (~2x covering instructions between issue and use).
//
// Proven invariants kept: PSTR=40 physical stride (80 B; SLOTS=32's 64 B
// stride was an 8-way bank conflict, round 5), logical-32 ring (&31 ->
// compile-time bases 24/8), launch_bounds(256,4) (cap 128; caps 64/85 both
// spilled -- tripwire WRITE_SIZE), fire-and-forget epilogue (fused finalize's
// fence+RMW cost ~130us, rounds 1-2), packed f32 math, read-before-write WAR
// ring discipline (per-wave in-order DS).
__global__ __launch_bounds__(256, 4) void ssim_kernel(
    const float* __restrict__ pred, const float* __restrict__ target,
    float* __restrict__ ws_sum)
{
    // ring[wave][pipe][ch][col][PSTR], bf16: 4*2*4*16*40*2 = 40960 B
    __shared__ __align__(16) short ring[4][2][4][16][PSTR];
    __shared__ float red[4];

    const int tid = threadIdx.x;
    const int wv = tid >> 6;
    const int lane = tid & 63;
    const int m = lane & 15;     // A-row / B-col / C-col index
    const int quad = lane >> 4;  // k-group / C-row-group

    // Gaussian weights, sigma=1.5
    float wsum = 0.f;
#pragma unroll
    for (int k = 0; k < KS; ++k) {
        float d = (float)(k - 5);
        wsum += __expf(-d * d * (1.0f / 4.5f));
    }
    const float invs = 1.0f / wsum;

    // Banded weight fragment: value at k=quad*8+j is w[k - m - 3] (0 outside band).
    // Serves as B in h-mfma (B[k][n]=w[k-n-3]) and A in v-mfma (A[m][k]=w[k-m-3]).
    short8 Wf;
    {
        union { short8 v; unsigned u[4]; } W;
#pragma unroll
        for (int jj = 0; jj < 4; ++jj) {
            float v0, v1;
            {
                int idx = quad * 8 + 2 * jj - m - 3;
                float d = (float)(idx - 5);
                v0 = (idx >= 0 && idx < KS) ? __expf(-d * d * (1.0f / 4.5f)) * invs : 0.f;
            }
            {
                int idx = quad * 8 + 2 * jj + 1 - m - 3;
                float d = (float)(idx - 5);
                v1 = (idx >= 0 && idx < KS) ? __expf(-d * d * (1.0f / 4.5f)) * invs : 0.f;
            }
            W.u[jj] = pk2bf_rne(v0, v1);
        }
        Wf = W.v;
    }

    const size_t poff = (size_t)blockIdx.z * HH * WW;
    const int Y0 = blockIdx.y * BY;

    // Per-pipe column bases: pipe0 = cols [XA,XA+16), pipe1 = +64.
    const int XA = blockIdx.x * BX + wv * 16;
    const int cA = XA - 8 + quad * 8;
    const int cB = cA + 64;
    const bool okA0 = (unsigned)cA < (unsigned)WW;
    const bool okA1 = (unsigned)(cA + 4) < (unsigned)WW;
    const bool okB0 = (unsigned)cB < (unsigned)WW;
    const bool okB1 = (unsigned)(cB + 4) < (unsigned)WW;
    const float* __restrict__ pcA = pred + poff + cA;
    const float* __restrict__ tcA = target + poff + cA;
    const float* __restrict__ pcB = pred + poff + cB;
    const float* __restrict__ tcB = target + poff + cB;

    const float2v C1v = {1.0e-4f, 1.0e-4f};
    const float2v C2v = {9.0e-4f, 9.0e-4f};
    float lsum = 0.f;
    const floatx4 z = {0.f, 0.f, 0.f, 0.f};

    // load chunk k's raw rows for one pipe (zero-padded outside the image)
    auto load_raw = [&](const float* __restrict__ pc, const float* __restrict__ tc,
                        bool ok0, bool ok1, int k) -> Raw {
        Raw r;
        r.p0 = make_float4(0, 0, 0, 0); r.p1 = make_float4(0, 0, 0, 0);
        r.t0 = make_float4(0, 0, 0, 0); r.t1 = make_float4(0, 0, 0, 0);
        const int row = Y0 + CHK * k - 8 + m;
        if ((unsigned)row < (unsigned)HH) {
            const float* pr = pc + (size_t)row * WW;
            const float* tr = tc + (size_t)row * WW;
            if (ok0) { r.p0 = *(const float4*)pr;       r.t0 = *(const float4*)tr; }
            if (ok1) { r.p1 = *(const float4*)(pr + 4); r.t1 = *(const float4*)(tr + 4); }
        }
        return r;
    };

    // h-step: pack raw -> bf16 frags (packed f32 math), 4 MFMA, pack D -> ring
    auto h_step = [&](int pipe, const Raw& r, int sb) {
        const float2v pa[4] = {{r.p0.x, r.p0.y}, {r.p0.z, r.p0.w},
                               {r.p1.x, r.p1.y}, {r.p1.z, r.p1.w}};
        const float2v tb[4] = {{r.t0.x, r.t0.y}, {r.t0.z, r.t0.w},
                               {r.t1.x, r.t1.y}, {r.t1.z, r.t1.w}};
        union { short8 v; unsigned u[4]; } Fp, Ft, Fq, Fpt;
#pragma unroll
        for (int jj = 0; jj < 4; ++jj) {
            Fp.u[jj]  = pkbf2(pa[jj]);
            Ft.u[jj]  = pkbf2(tb[jj]);
            // q = p^2 + t^2 : packed mul+fma, ONE bf16 quantization
            Fq.u[jj]  = pkbf2(pa[jj] * pa[jj] + tb[jj] * tb[jj]);
            Fpt.u[jj] = pkbf2(pa[jj] * tb[jj]);
        }
        floatx4 Dp  = __builtin_amdgcn_mfma_f32_16x16x32_bf16(Fp.v,  Wf, z, 0, 0, 0);
        floatx4 Dt  = __builtin_amdgcn_mfma_f32_16x16x32_bf16(Ft.v,  Wf, z, 0, 0, 0);
        floatx4 Dq  = __builtin_amdgcn_mfma_f32_16x16x32_bf16(Fq.v,  Wf, z, 0, 0, 0);
        floatx4 Dpt = __builtin_amdgcn_mfma_f32_16x16x32_bf16(Fpt.v, Wf, z, 0, 0, 0);
        // C-layout: col = lane&15 (=m), rows = quad*4 + reg -> slots sb+quad*4+reg
        const int slot = (sb + quad * 4) & (RING - 1);
        uint2 v;
        v.x = pkbf2(float2v{Dp[0],  Dp[1]});  v.y = pkbf2(float2v{Dp[2],  Dp[3]});
        *(uint2*)&ring[wv][pipe][0][m][slot] = v;
        v.x = pkbf2(float2v{Dt[0],  Dt[1]});  v.y = pkbf2(float2v{Dt[2],  Dt[3]});
        *(uint2*)&ring[wv][pipe][1][m][slot] = v;
        v.x = pkbf2(float2v{Dq[0],  Dq[1]});  v.y = pkbf2(float2v{Dq[2],  Dq[3]});
        *(uint2*)&ring[wv][pipe][2][m][slot] = v;
        v.x = pkbf2(float2v{Dpt[0], Dpt[1]}); v.y = pkbf2(float2v{Dpt[2], Dpt[3]});
        *(uint2*)&ring[wv][pipe][3][m][slot] = v;
    };

    // v-frag reads (must precede the same-iteration h-write in program order)
    auto vread = [&](int pipe, int base) -> Frags {
        const int sq = (base + quad * 8) & (RING - 1);   // 0/8/16/24: never in pad
        Frags f;
        f.p  = *(const short8*)&ring[wv][pipe][0][m][sq];
        f.t  = *(const short8*)&ring[wv][pipe][1][m][sq];
        f.q  = *(const short8*)&ring[wv][pipe][2][m][sq];
        f.pt = *(const short8*)&ring[wv][pipe][3][m][sq];
        return f;
    };

    // v-blur + SSIM (packed f32 pairs)
    auto vfin = [&](const Frags& f) {
        floatx4 Mp  = __builtin_amdgcn_mfma_f32_16x16x32_bf16(Wf, f.p,  z, 0, 0, 0);
        floatx4 Mt  = __builtin_amdgcn_mfma_f32_16x16x32_bf16(Wf, f.t,  z, 0, 0, 0);
        floatx4 Mq  = __builtin_amdgcn_mfma_f32_16x16x32_bf16(Wf, f.q,  z, 0, 0, 0);
        floatx4 Mpt = __builtin_amdgcn_mfma_f32_16x16x32_bf16(Wf, f.pt, z, 0, 0, 0);
#pragma unroll
        for (int h = 0; h < 2; ++h) {
            const float2v mup = {Mp[2*h],  Mp[2*h+1]};
            const float2v mut = {Mt[2*h],  Mt[2*h+1]};
            const float2v mq  = {Mq[2*h],  Mq[2*h+1]};
            const float2v mpt = {Mpt[2*h], Mpt[2*h+1]};
            const float2v mupsq = mup * mup, mutsq = mut * mut, mucr = mup * mut;
            const float2v scr = mpt - mucr;
            const float2v n1 = mucr + mucr + C1v;
            const float2v n2 = scr + scr + C2v;
            const float2v d1 = mupsq + mutsq + C1v;
            const float2v d2 = (mq - mupsq - mutsq) + C2v;   // sp2+st2+C2
            const float2v num = n1 * n2, den = d1 * d2;
            lsum += __fdividef(num[0], den[0]) + __fdividef(num[1], den[1]);
        }
    };

    // Prologue: chunks 0,1 h-blurred (bases 24,8); chunk 2 left in the buffers.
    Raw CA, CB;
    CA = load_raw(pcA, tcA, okA0, okA1, 0);
    CB = load_raw(pcB, tcB, okB0, okB1, 0);
    h_step(0, CA, 24); h_step(1, CB, 24);
    CA = load_raw(pcA, tcA, okA0, okA1, 1);
    CB = load_raw(pcB, tcB, okB0, okB1, 1);
    h_step(0, CA, 8);  h_step(1, CB, 8);
    CA = load_raw(pcA, tcA, okA0, okA1, 2);
    CB = load_raw(pcB, tcB, okB0, okB1, 2);

    // Main bodies i=0..5 (pairs: even base 24, odd base 8). Body i:
    //   vread(i) both pipes -> h(chunk i+2) both pipes (waits its own pipe's
    //   loads from body i-1; the OTHER pipe's ds/MFMA work covers the wait)
    //   -> reload both buffers (chunk i+3) -> v-MFMA + SSIM both pipes.
#pragma unroll 1
    for (int ii = 0; ii < 6; ii += 2) {
        {   // body ii, base 24: h chunk ii+2, load chunk ii+3
            Frags FA = vread(0, 24), FB = vread(1, 24);
            h_step(0, CA, 24);
            h_step(1, CB, 24);
            CA = load_raw(pcA, tcA, okA0, okA1, ii + 3);
            CB = load_raw(pcB, tcB, okB0, okB1, ii + 3);
            vfin(FA); vfin(FB);
        }
        {   // body ii+1, base 8: h chunk ii+3, load chunk ii+4 (<= 8)
            Frags FA = vread(0, 8), FB = vread(1, 8);
            h_step(0, CA, 8);
            h_step(1, CB, 8);
            CA = load_raw(pcA, tcA, okA0, okA1, ii + 4);
            CB = load_raw(pcB, tcB, okB0, okB1, ii + 4);
            vfin(FA); vfin(FB);
        }
    }
    // Body 6 (base 24): h chunk 8 (last), no loads.
    {
        Frags FA = vread(0, 24), FB = vread(1, 24);
        h_step(0, CA, 24);
        h_step(1, CB, 24);
        vfin(FA); vfin(FB);
    }
    // Body 7 (base 8): no h-step.
    {
        Frags FA = vread(0, 8), FB = vread(1, 8);
        vfin(FA); vfin(FB);
    }

    // wave reduce -> block reduce -> ONE fire-and-forget atomic per block.
#pragma unroll
    for (int off = 32; off > 0; off >>= 1) lsum += __shfl_down(lsum, off, 64);
    if (lane == 0) red[wv] = lsum;
    __syncthreads();
    if (tid == 0) {
        atomicAdd(ws_sum, red[0] + red[1] + red[2] + red[3]);
    }
}

__global__ void finalize_kernel(const float* __restrict__ ws_sum,
                                float* __restrict__ out) {
    out[0] = 1.0f - ws_sum[0] * (1.0f / 12582912.0f);  // N = 16*3*512*512
}

extern "C" void kernel_launch(void* const* d_in, const int* in_sizes, int n_in,
                              void* d_out, int out_size, void* d_ws, size_t ws_size,
                              hipStream_t stream) {
    const float* pred = (const float*)d_in[0];
    const float* target = (const float*)d_in[1];
    float* out = (float*)d_out;
    float* ws = (float*)d_ws;

    hipMemsetAsync(ws, 0, sizeof(float), stream);       // graph-capturable
    dim3 grid(WW / BX, HH / BY, NPLANE);                // 4 x 4 x 48 = 768 blocks
    ssim_kernel<<<grid, 256, 0, stream>>>(pred, target, ws);
    finalize_kernel<<<1, 1, 0, stream>>>(ws, out);
}